// Round 4
// baseline (338.541 us; speedup 1.0000x reference)
//
#include <hip/hip_runtime.h>

#define BB   4
#define NN   256
#define TT   4096
#define DD   128      // SIM_DIM
#define LK   101      // LOOKUP
#define PADK 50
#define OD   128      // OUT_DIM
#define ROWS 164      // 64 + LK - 1 rows of halo'd proj window
#define RSTR 33       // band: row stride in float4 units (132 floats, +4 pad)
#define FSTR 264      // fused: fs row stride floats (16B-aligned, swizzled banks)

// ---------------- kernel 1: one-time weight transposes ----------------
__global__ __launch_bounds__(256) void transpose_w_kernel(
    const float* __restrict__ w_proj, const float* __restrict__ w_fc,
    float* __restrict__ w_t, float* __restrict__ wfc_t) {
  int idx = blockIdx.x * 256 + threadIdx.x;
  int stride = gridDim.x * 256;
  for (int i = idx; i < DD * NN; i += stride) {
    int d = i / NN, n = i - d * NN;
    w_t[n * DD + d] = w_proj[i];
  }
  for (int i = idx; i < OD * LK; i += stride) {
    int o = i / LK, j = i - o * LK;
    wfc_t[j * OD + o] = w_fc[i];
  }
}

// ------------- kernel 2: fused mean-pool + projection + L2 normalize -------------
// 512 blocks (b, 32-t tile) x 512 threads; 2 blocks/CU -> 4 waves/SIMD.
// Phase A: stream x slab (1.57 MB/block), pool 48->1 in regs, store fs[t][n] (swizzled).
// Phase B: proj GEMM slice; wave w -> d-slice 16 (uniform), lane&31 = t, lane>>5 = K-half.
__global__ __launch_bounds__(512) void pool_proj_kernel(
    const float* __restrict__ x, const float* __restrict__ w_t,
    float* __restrict__ projn) {
  __shared__ float fs[32 * FSTR];   // pooled feat, [t][n] swizzled
  __shared__ float ss[8 * 32];      // per-wave norm partials
  int b = blockIdx.x >> 7;
  int t0 = (blockIdx.x & 127) << 5;
  int tid = threadIdx.x;

  // ---- Phase A: pool ----
#pragma unroll
  for (int i = 0; i < 16; ++i) {
    int p = i * 512 + tid;          // 0..8191
    int n = p >> 5, t = p & 31;
    const float4* row = (const float4*)(x + ((size_t)(b * NN + n) * TT + (t0 + t)) * 48);
    float s0 = 0.f, s1 = 0.f, s2 = 0.f, s3 = 0.f;
#pragma unroll
    for (int q = 0; q < 3; ++q) {
      float4 v0 = row[q * 4 + 0], v1 = row[q * 4 + 1];
      float4 v2 = row[q * 4 + 2], v3 = row[q * 4 + 3];
      s0 += v0.x + v0.y + v0.z + v0.w;
      s1 += v1.x + v1.y + v1.z + v1.w;
      s2 += v2.x + v2.y + v2.z + v2.w;
      s3 += v3.x + v3.y + v3.z + v3.w;
    }
    int slot = n >> 2;
    int slots = slot ^ (t & 15);                 // XOR swizzle (float4 granularity)
    fs[t * FSTR + (slots << 2) + (n & 3)] = ((s0 + s1) + (s2 + s3)) * (1.0f / 48.0f);
  }
  __syncthreads();

  // ---- Phase B: projection ----
  int w = tid >> 6, lane = tid & 63;
  int t = lane & 31, h = lane >> 5;
  int d0 = __builtin_amdgcn_readfirstlane((tid >> 6) * 16);
  float acc[16];
#pragma unroll
  for (int k = 0; k < 16; ++k) acc[k] = 0.f;

  const float* fsr = fs + t * FSTR;
  for (int c = 0; c < 32; ++c) {
    int slot = h * 32 + c;
    float4 f4 = *(const float4*)(fsr + ((slot ^ (t & 15)) << 2));
    int nb = (h * 128 + c * 4);
    const float* wrow = w_t + nb * DD + d0;      // uniform address
#pragma unroll
    for (int q = 0; q < 4; ++q) {
      float fq = (q == 0) ? f4.x : (q == 1) ? f4.y : (q == 2) ? f4.z : f4.w;
      const float4* wv4 = (const float4*)(wrow + q * DD);
#pragma unroll
      for (int k = 0; k < 4; ++k) {
        float4 wv = wv4[k];
        acc[4 * k + 0] += wv.x * fq;
        acc[4 * k + 1] += wv.y * fq;
        acc[4 * k + 2] += wv.z * fq;
        acc[4 * k + 3] += wv.w * fq;
      }
    }
  }
  // combine K-halves
#pragma unroll
  for (int k = 0; k < 16; ++k) acc[k] += __shfl_xor(acc[k], 32, 64);

  float s2 = 0.f;
#pragma unroll
  for (int k = 0; k < 16; ++k) s2 += acc[k] * acc[k];
  if (h == 0) ss[w * 32 + t] = s2;
  __syncthreads();
  float tot = 0.f;
#pragma unroll
  for (int q = 0; q < 8; ++q) tot += ss[q * 32 + t];
  float inv = 1.0f / fmaxf(sqrtf(tot), 1e-12f);

  // half h writes k-range [8h, 8h+8)
  float4* po = (float4*)(projn + ((size_t)(b * TT + t0 + t)) * DD + d0 + h * 8);
#pragma unroll
  for (int k = 0; k < 2; ++k) {
    int kb = h * 8 + k * 4;
    float4 o;
    o.x = acc[kb + 0] * inv;
    o.y = acc[kb + 1] * inv;
    o.z = acc[kb + 2] * inv;
    o.w = acc[kb + 3] * inv;
    po[k] = o;
  }
}

// ---------------- kernel 3: banded cosine sims + FC + ReLU ----------------
// 512 threads = 8 waves. Phase 1: own row (lane tt) in 128 VGPRs, scan s
// (21/wave), other row = wave-uniform LDS broadcast, 4-way accumulator split.
__global__ __launch_bounds__(512, 1) void band_fc_kernel(
    const float* __restrict__ projn, const float* __restrict__ wfc_t,
    const float* __restrict__ b_fc, float* __restrict__ out) {
  extern __shared__ float4 smemC[];
  float4* p4 = smemC;                            // [ROWS][RSTR]
  float* band = (float*)(smemC + ROWS * RSTR);   // [64][101]
  int b = blockIdx.x >> 6;
  int t0 = (blockIdx.x & 63) << 6;
  int tid = threadIdx.x;

  const float4* pg = (const float4*)projn;
  for (int i = tid; i < ROWS * 32; i += 512) {
    int r = i >> 5, c = i & 31;
    int t = t0 + r - PADK;
    float4 v = make_float4(0.f, 0.f, 0.f, 0.f);
    if (t >= 0 && t < TT) v = pg[(((size_t)b * TT + t) << 5) + c];
    p4[r * RSTR + c] = v;
  }
  __syncthreads();

  int w = tid >> 6, tt = tid & 63;

  float4 own[32];
#pragma unroll
  for (int c = 0; c < 32; ++c) own[c] = p4[(tt + PADK) * RSTR + c];

  int s0 = w * 21;
  int sEnd = (s0 + 21 < ROWS) ? (s0 + 21) : ROWS;
  for (int s = s0; s < sEnd; ++s) {
    float a0 = 0.f, a1 = 0.f, a2 = 0.f, a3 = 0.f;  // 4 independent chains
#pragma unroll
    for (int c = 0; c < 32; ++c) {
      float4 ov = p4[s * RSTR + c];   // wave-uniform -> LDS broadcast
      a0 += own[c].x * ov.x;
      a1 += own[c].y * ov.y;
      a2 += own[c].z * ov.z;
      a3 += own[c].w * ov.w;
    }
    int j = s - tt;
    if (j >= 0 && j < LK) band[tt * LK + j] = (a0 + a1) + (a2 + a3);
  }
  __syncthreads();

  int o0u = __builtin_amdgcn_readfirstlane((tid >> 6) * 16);
  float acc[16];
  const float4* bf4 = (const float4*)(b_fc + o0u);
#pragma unroll
  for (int k = 0; k < 4; ++k) {
    float4 bv = bf4[k];
    acc[4 * k + 0] = bv.x; acc[4 * k + 1] = bv.y;
    acc[4 * k + 2] = bv.z; acc[4 * k + 3] = bv.w;
  }
#pragma unroll 2
  for (int j = 0; j < LK; ++j) {
    float bv = band[tt * LK + j];                 // gcd(101,32)=1: conflict-free
    const float4* wr = (const float4*)(wfc_t + j * OD + o0u);  // uniform
#pragma unroll
    for (int k = 0; k < 4; ++k) {
      float4 wv = wr[k];
      acc[4 * k + 0] += wv.x * bv;
      acc[4 * k + 1] += wv.y * bv;
      acc[4 * k + 2] += wv.z * bv;
      acc[4 * k + 3] += wv.w * bv;
    }
  }
  float4* og = (float4*)(out + ((size_t)(b * TT + t0 + tt)) * OD + o0u);
#pragma unroll
  for (int k = 0; k < 4; ++k) {
    float4 o;
    o.x = fmaxf(acc[4 * k + 0], 0.f);
    o.y = fmaxf(acc[4 * k + 1], 0.f);
    o.z = fmaxf(acc[4 * k + 2], 0.f);
    o.w = fmaxf(acc[4 * k + 3], 0.f);
    og[k] = o;
  }
}

extern "C" void kernel_launch(void* const* d_in, const int* in_sizes, int n_in,
                              void* d_out, int out_size, void* d_ws, size_t ws_size,
                              hipStream_t stream) {
  const float* x      = (const float*)d_in[0];
  const float* w_proj = (const float*)d_in[1];
  const float* w_fc   = (const float*)d_in[2];
  const float* b_fc   = (const float*)d_in[3];
  float* out = (float*)d_out;

  char* ws = (char*)d_ws;
  float* projn = (float*)ws;                       // B*T*D f32 = 8,388,608 B
  float* w_t   = (float*)(ws + 8388608);           // N*D f32   =   131,072 B
  float* wfc_t = (float*)(ws + 8388608 + 131072);  // LK*OD f32 =    51,712 B

  size_t smC = (size_t)ROWS * RSTR * sizeof(float4) + (size_t)64 * LK * sizeof(float); // 112,448 B
  (void)hipFuncSetAttribute((const void*)band_fc_kernel,
                      hipFuncAttributeMaxDynamicSharedMemorySize, (int)smC);

  transpose_w_kernel<<<64, 256, 0, stream>>>(w_proj, w_fc, w_t, wfc_t);
  pool_proj_kernel<<<BB * (TT / 32), 512, 0, stream>>>(x, w_t, projn);
  band_fc_kernel<<<BB * (TT / 64), 512, smC, stream>>>(projn, wfc_t, b_fc, out);
}

// Round 5
// 236.553 us; speedup vs baseline: 1.4311x; 1.4311x over previous
//
#include <hip/hip_runtime.h>

#define BB   4
#define NN   256
#define TT   4096
#define DD   128      // SIM_DIM
#define LK   101      // LOOKUP
#define PADK 50
#define OD   128      // OUT_DIM
#define ROWS 164      // 64 + LK - 1 rows of halo'd proj window
#define RSTR 33       // band: row stride in float4 units (132 floats, +4 pad)
#define TTILE 32      // t-tile per fused block
#define FSTR 260      // fs row stride floats: 260/4=65 ≡ 1 mod 32 -> conflict-free b128

typedef float vfloat4 __attribute__((ext_vector_type(4)));

// ---------------- kernel 1: one-time weight transposes ----------------
__global__ __launch_bounds__(256) void transpose_w_kernel(
    const float* __restrict__ w_proj, const float* __restrict__ w_fc,
    float* __restrict__ w_t, float* __restrict__ wfc_t) {
  int idx = blockIdx.x * 256 + threadIdx.x;
  int stride = gridDim.x * 256;
  for (int i = idx; i < DD * NN; i += stride) {
    int d = i / NN, n = i - d * NN;
    w_t[n * DD + d] = w_proj[i];
  }
  for (int i = idx; i < OD * LK; i += stride) {
    int o = i / LK, j = i - o * LK;
    wfc_t[j * OD + o] = w_fc[i];
  }
}

// ------------- kernel 2: fused mean-pool + projection + L2 normalize -------------
// 512 blocks (b, 32-t tile) x 512 threads, 46KB LDS -> 2 blocks/CU.
// Phase A: 64 iters; each reads 4 n-rows x 32 t x 48 f = 1536 float4 COALESCED
//   (3/thread), software-pipelined across the per-iter barrier; LDS partials
//   (12->1 reduce) produce fs[t][n].
// Phase B: proj; wave w = d-slice 16, lane&31 = t, lane>>5 = K-half; conflict-free
//   fs reads; uniform w_t rows; shfl_xor(32) K-combine; norm; write.
__global__ __launch_bounds__(512) void pool_proj_kernel(
    const float* __restrict__ x, const float* __restrict__ w_t,
    float* __restrict__ projn) {
  __shared__ float fs[TTILE * FSTR];   // 33.3 KB pooled feat [t][n]
  __shared__ float part[2][1536];      // 12 KB partials (double-buffered)
  __shared__ float ss[8 * 32];         // norm partials
  int b = blockIdx.x >> 7;
  int t0 = (blockIdx.x & 127) * TTILE;
  int tid = threadIdx.x;

  // ---- Phase A ----
  const vfloat4* x4 = (const vfloat4*)x;
  size_t base4 = ((size_t)(b * NN) * TT + t0) * 12;  // float4 units
  int gj[3], nj[3], rj[3];
#pragma unroll
  for (int j = 0; j < 3; ++j) {
    int g = tid + 512 * j;          // 0..1535
    gj[j] = g;
    nj[j] = g / 384;                // local n' 0..3
    rj[j] = g - 384 * nj[j];        // within-row float4 index
  }

  vfloat4 v[3];
#pragma unroll
  for (int j = 0; j < 3; ++j)
    v[j] = __builtin_nontemporal_load(&x4[base4 + (size_t)nj[j] * 49152 + rj[j]]);

  for (int k = 0; k < 64; ++k) {
    vfloat4 nxt[3];
    int kn = (k < 63) ? k + 1 : 63;   // clamp: last prefetch re-reads, unused
#pragma unroll
    for (int j = 0; j < 3; ++j)
      nxt[j] = __builtin_nontemporal_load(
          &x4[base4 + (size_t)(kn * 4 + nj[j]) * 49152 + rj[j]]);

    float* pb = part[k & 1];
#pragma unroll
    for (int j = 0; j < 3; ++j)
      pb[gj[j]] = (v[j].x + v[j].y) + (v[j].z + v[j].w);  // waits vmcnt on v only
    __syncthreads();

    if (tid < 128) {
      int nl = tid >> 5, t = tid & 31;
      const float* pp = part[k & 1] + nl * 384 + t * 12;
      float s0 = 0.f, s1 = 0.f;
#pragma unroll
      for (int i = 0; i < 6; ++i) { s0 += pp[i]; s1 += pp[6 + i]; }
      fs[t * FSTR + (k * 4 + nl)] = (s0 + s1) * (1.0f / 48.0f);
    }
#pragma unroll
    for (int j = 0; j < 3; ++j) v[j] = nxt[j];
  }
  __syncthreads();

  // ---- Phase B: projection ----
  int w = tid >> 6, lane = tid & 63;
  int t = lane & 31, h = lane >> 5;
  int d0 = __builtin_amdgcn_readfirstlane((tid >> 6) * 16);
  float acc[16];
#pragma unroll
  for (int k = 0; k < 16; ++k) acc[k] = 0.f;

  const float* fsr = fs + t * FSTR + h * 128;
  for (int c = 0; c < 32; ++c) {
    float4 f4 = *(const float4*)(fsr + 4 * c);      // conflict-free b128
    const float* wrow = w_t + (h * 128 + 4 * c) * DD + d0;  // uniform
#pragma unroll
    for (int q = 0; q < 4; ++q) {
      float fq = (q == 0) ? f4.x : (q == 1) ? f4.y : (q == 2) ? f4.z : f4.w;
      const float4* wv4 = (const float4*)(wrow + q * DD);
#pragma unroll
      for (int k = 0; k < 4; ++k) {
        float4 wv = wv4[k];
        acc[4 * k + 0] += wv.x * fq;
        acc[4 * k + 1] += wv.y * fq;
        acc[4 * k + 2] += wv.z * fq;
        acc[4 * k + 3] += wv.w * fq;
      }
    }
  }
#pragma unroll
  for (int k = 0; k < 16; ++k) acc[k] += __shfl_xor(acc[k], 32, 64);

  float s2 = 0.f;
#pragma unroll
  for (int k = 0; k < 16; ++k) s2 += acc[k] * acc[k];
  if (h == 0) ss[w * 32 + t] = s2;
  __syncthreads();
  float tot = 0.f;
#pragma unroll
  for (int q = 0; q < 8; ++q) tot += ss[q * 32 + t];
  float inv = 1.0f / fmaxf(sqrtf(tot), 1e-12f);

  float4* po = (float4*)(projn + ((size_t)(b * TT + t0 + t)) * DD + d0 + h * 8);
#pragma unroll
  for (int k = 0; k < 2; ++k) {
    int kb = h * 8 + k * 4;
    float4 o;
    o.x = acc[kb + 0] * inv;
    o.y = acc[kb + 1] * inv;
    o.z = acc[kb + 2] * inv;
    o.w = acc[kb + 3] * inv;
    po[k] = o;
  }
}

// ---------------- kernel 3: banded cosine sims + FC + ReLU ----------------
// 512 threads = 8 waves. Phase 1: own row (lane tt) in 128 VGPRs, scan s
// (21/wave), other row = wave-uniform LDS broadcast, 4 independent FMA chains.
__global__ __launch_bounds__(512, 1) void band_fc_kernel(
    const float* __restrict__ projn, const float* __restrict__ wfc_t,
    const float* __restrict__ b_fc, float* __restrict__ out) {
  extern __shared__ float4 smemC[];
  float4* p4 = smemC;                            // [ROWS][RSTR]
  float* band = (float*)(smemC + ROWS * RSTR);   // [64][101]
  int b = blockIdx.x >> 6;
  int t0 = (blockIdx.x & 63) << 6;
  int tid = threadIdx.x;

  const float4* pg = (const float4*)projn;
  for (int i = tid; i < ROWS * 32; i += 512) {
    int r = i >> 5, c = i & 31;
    int t = t0 + r - PADK;
    float4 v = make_float4(0.f, 0.f, 0.f, 0.f);
    if (t >= 0 && t < TT) v = pg[(((size_t)b * TT + t) << 5) + c];
    p4[r * RSTR + c] = v;
  }
  __syncthreads();

  int w = tid >> 6, tt = tid & 63;

  float4 own[32];
#pragma unroll
  for (int c = 0; c < 32; ++c) own[c] = p4[(tt + PADK) * RSTR + c];

  int s0 = w * 21;
  int sEnd = (s0 + 21 < ROWS) ? (s0 + 21) : ROWS;
  for (int s = s0; s < sEnd; ++s) {
    float a0 = 0.f, a1 = 0.f, a2 = 0.f, a3 = 0.f;
#pragma unroll
    for (int c = 0; c < 32; ++c) {
      float4 ov = p4[s * RSTR + c];   // wave-uniform -> LDS broadcast
      a0 += own[c].x * ov.x;
      a1 += own[c].y * ov.y;
      a2 += own[c].z * ov.z;
      a3 += own[c].w * ov.w;
    }
    int j = s - tt;
    if (j >= 0 && j < LK) band[tt * LK + j] = (a0 + a1) + (a2 + a3);
  }
  __syncthreads();

  int o0u = __builtin_amdgcn_readfirstlane((tid >> 6) * 16);
  float acc[16];
  const float4* bf4 = (const float4*)(b_fc + o0u);
#pragma unroll
  for (int k = 0; k < 4; ++k) {
    float4 bv = bf4[k];
    acc[4 * k + 0] = bv.x; acc[4 * k + 1] = bv.y;
    acc[4 * k + 2] = bv.z; acc[4 * k + 3] = bv.w;
  }
#pragma unroll 2
  for (int j = 0; j < LK; ++j) {
    float bv = band[tt * LK + j];                 // gcd(101,32)=1: conflict-free
    const float4* wr = (const float4*)(wfc_t + j * OD + o0u);  // uniform
#pragma unroll
    for (int k = 0; k < 4; ++k) {
      float4 wv = wr[k];
      acc[4 * k + 0] += wv.x * bv;
      acc[4 * k + 1] += wv.y * bv;
      acc[4 * k + 2] += wv.z * bv;
      acc[4 * k + 3] += wv.w * bv;
    }
  }
  float4* og = (float4*)(out + ((size_t)(b * TT + t0 + tt)) * OD + o0u);
#pragma unroll
  for (int k = 0; k < 4; ++k) {
    float4 o;
    o.x = fmaxf(acc[4 * k + 0], 0.f);
    o.y = fmaxf(acc[4 * k + 1], 0.f);
    o.z = fmaxf(acc[4 * k + 2], 0.f);
    o.w = fmaxf(acc[4 * k + 3], 0.f);
    og[k] = o;
  }
}

extern "C" void kernel_launch(void* const* d_in, const int* in_sizes, int n_in,
                              void* d_out, int out_size, void* d_ws, size_t ws_size,
                              hipStream_t stream) {
  const float* x      = (const float*)d_in[0];
  const float* w_proj = (const float*)d_in[1];
  const float* w_fc   = (const float*)d_in[2];
  const float* b_fc   = (const float*)d_in[3];
  float* out = (float*)d_out;

  char* ws = (char*)d_ws;
  float* projn = (float*)ws;                       // B*T*D f32 = 8,388,608 B
  float* w_t   = (float*)(ws + 8388608);           // N*D f32   =   131,072 B
  float* wfc_t = (float*)(ws + 8388608 + 131072);  // LK*OD f32 =    51,712 B

  size_t smC = (size_t)ROWS * RSTR * sizeof(float4) + (size_t)64 * LK * sizeof(float); // 112,448 B
  (void)hipFuncSetAttribute((const void*)band_fc_kernel,
                      hipFuncAttributeMaxDynamicSharedMemorySize, (int)smC);

  transpose_w_kernel<<<64, 256, 0, stream>>>(w_proj, w_fc, w_t, wfc_t);
  pool_proj_kernel<<<BB * (TT / TTILE), 512, 0, stream>>>(x, w_t, projn);
  band_fc_kernel<<<BB * (TT / 64), 512, smC, stream>>>(projn, wfc_t, b_fc, out);
}